// Round 11
// baseline (304.121 us; speedup 1.0000x reference)
//
#include <hip/hip_runtime.h>
#include <math.h>

// ---------------------------------------------------------------------------
// CoarseMVSNet, de-fused fp16 pipeline (R11):
//   setup_mats_kernel    : mats + fp16 weight relayout (1 dispatch)
//   transpose_f16_kernel : LDS-tiled coalesced fp32 (V,C,H,W) -> fp16 (V,H,W,C)
//   gather_var_kernel    : 1 thread = 8 channels of var volume, fp32 math.
//                          GROUP-SPLIT layout [d][cg][pix][8ch].
//   conv_cost_kernel     : 3x3x3 conv, barrier-free per-wave staging,
//                          WEIGHTS PRELOADED INTO VGPRS (R10 post-mortem:
//                          27 uniform weight loads/interval can't be hoisted
//                          -- needs 108 SGPRs > budget -- so every interval
//                          re-paid ~27 s_load+lgkm waits; VALU was 20% with
//                          no pipe saturated). Depth-3 per-wave pipeline.
//   range/epilogue       : fp32 softmax head.
// __launch_bounds__(256) ONLY (R2: (256,4) forced VGPR->64, 4.2 GB spill).
// ---------------------------------------------------------------------------

typedef _Float16 half2_t __attribute__((ext_vector_type(2)));
typedef _Float16 half8_t __attribute__((ext_vector_type(8)));

union U4H { uint4 u; half2_t h[4]; };
union U2H { uint2 u; half2_t h[2]; };

static __device__ inline float fdot2f(half2_t a, half2_t b, float c) {
#if __has_builtin(__builtin_amdgcn_fdot2)
  return __builtin_amdgcn_fdot2(a, b, c, false);
#else
  return c + (float)a[0] * (float)b[0] + (float)a[1] * (float)b[1];
#endif
}

// mats (thread 0) + fp16 weight relayout w[c][kd][kh][kw] -> w2h[(t*3+kd)][c]
__global__ void setup_mats_kernel(const float* __restrict__ proj1,
                                  const float* __restrict__ proj2,
                                  const float* __restrict__ depthv, int nd,
                                  float* __restrict__ ws,
                                  const float* __restrict__ w1,
                                  const float* __restrict__ w2,
                                  _Float16* __restrict__ w2a,
                                  _Float16* __restrict__ w2b) {
  const int tid = threadIdx.x;
  if (w2a != nullptr) {
    for (int i = tid; i < 27 * 32; i += 256) {
      int c = i % 32, r = i / 32, kd = r % 3, t = r / 3;
      w2a[(t * 3 + kd) * 32 + c] = (_Float16)w1[c * 27 + kd * 9 + t];
    }
    for (int i = tid; i < 27 * 16; i += 256) {
      int c = i % 16, r = i / 16, kd = r % 3, t = r / 3;
      w2b[(t * 3 + kd) * 16 + c] = (_Float16)w2[c * 27 + kd * 9 + t];
    }
  }
  if (tid != 0) return;
  for (int s = 0; s < 2; ++s) {
    const float* P = s ? proj2 : proj1;  // (3,2,4,4) flat
    double comp[3][4][4];
    for (int v = 0; v < 3; ++v) {
      const float* E = P + v * 32;
      const float* K = P + v * 32 + 16;
      for (int r = 0; r < 3; ++r)
        for (int c = 0; c < 4; ++c) {
          double acc = 0.0;
          for (int k = 0; k < 3; ++k) acc += (double)K[r * 4 + k] * (double)E[k * 4 + c];
          comp[v][r][c] = acc;
        }
      for (int c = 0; c < 4; ++c) comp[v][3][c] = (double)E[12 + c];
    }
    double a[4][8];
    for (int r = 0; r < 4; ++r)
      for (int c = 0; c < 4; ++c) {
        a[r][c] = comp[0][r][c];
        a[r][4 + c] = (r == c) ? 1.0 : 0.0;
      }
    for (int col = 0; col < 4; ++col) {
      int piv = col;
      double best = fabs(a[col][col]);
      for (int r = col + 1; r < 4; ++r) {
        double t = fabs(a[r][col]);
        if (t > best) { best = t; piv = r; }
      }
      if (piv != col)
        for (int c = 0; c < 8; ++c) { double t = a[col][c]; a[col][c] = a[piv][c]; a[piv][c] = t; }
      double dv = a[col][col];
      for (int c = 0; c < 8; ++c) a[col][c] /= dv;
      for (int r = 0; r < 4; ++r)
        if (r != col) {
          double f = a[r][col];
          if (f != 0.0)
            for (int c = 0; c < 8; ++c) a[r][c] -= f * a[col][c];
        }
    }
    for (int v = 1; v < 3; ++v) {
      double Pm[3][4];
      for (int r = 0; r < 3; ++r)
        for (int c = 0; c < 4; ++c) {
          double acc = 0.0;
          for (int k = 0; k < 4; ++k) acc += comp[v][r][k] * a[k][4 + c];
          Pm[r][c] = acc;
        }
      float* o = ws + s * 24 + (v - 1) * 12;
      o[0] = (float)Pm[0][0]; o[1] = (float)Pm[0][1]; o[2] = (float)Pm[0][2];
      o[3] = (float)Pm[1][0]; o[4] = (float)Pm[1][1]; o[5] = (float)Pm[1][2];
      o[6] = (float)Pm[2][0]; o[7] = (float)Pm[2][1]; o[8] = (float)Pm[2][2];
      o[9] = (float)Pm[0][3]; o[10] = (float)Pm[1][3]; o[11] = (float)Pm[2][3];
    }
  }
  ws[48] = depthv[0];
  ws[49] = (depthv[nd - 1] - depthv[0]) / 47.0f;
}

// LDS-tiled coalesced transpose: fp32 (V,C,H,W) -> fp16 (V,H,W,C).
template <int C, int H, int W>
__global__ void transpose_f16_kernel(const float* __restrict__ in,
                                     _Float16* __restrict__ out) {
  __shared__ float s_t[C][33];
  const int v = blockIdx.z, h = blockIdx.y, w0 = blockIdx.x * 32;
  const int tid = threadIdx.x;
  for (int r = tid; r < C * 32; r += 256) {
    int c = r >> 5, w = r & 31;
    s_t[c][w] = in[((size_t)(v * C + c) * H + h) * W + w0 + w];
  }
  __syncthreads();
  for (int r = tid; r < 32 * C; r += 256) {
    int w = r / C, c = r - (r / C) * C;
    out[((size_t)(v * H + h) * W + w0 + w) * C + c] = (_Float16)s_t[c][w];
  }
}

// Per-pixel depth range for STAGE2: bilinear 2x upsample of d1/v1.
template <int D, int H, int W>
__device__ inline void stage2_range(const float* __restrict__ prev_d,
                                    const float* __restrict__ prev_v,
                                    int gy, int gx, float& base, float& st) {
  constexpr int SH = H / 2, SW = W / 2;
  float syf = 0.5f * (float)gy - 0.25f;
  float sxf = 0.5f * (float)gx - 0.25f;
  syf = fminf(fmaxf(syf, 0.0f), (float)(SH - 1));
  sxf = fminf(fmaxf(sxf, 0.0f), (float)(SW - 1));
  int sy0 = (int)syf, sx0 = (int)sxf;
  float fy2 = syf - (float)sy0, fx2 = sxf - (float)sx0;
  int sy1 = min(sy0 + 1, SH - 1), sx1 = min(sx0 + 1, SW - 1);
  int j00 = sy0 * SW + sx0, j01 = sy0 * SW + sx1;
  int j10 = sy1 * SW + sx0, j11 = sy1 * SW + sx1;
  float cd = (prev_d[j00] * (1.f - fx2) + prev_d[j01] * fx2) * (1.f - fy2) +
             (prev_d[j10] * (1.f - fx2) + prev_d[j11] * fx2) * fy2;
  float cv = (prev_v[j00] * (1.f - fx2) + prev_v[j01] * fx2) * (1.f - fy2) +
             (prev_v[j10] * (1.f - fx2) + prev_v[j11] * fx2) * fy2;
  float lo = -fminf(cd, cv);
  base = cd + lo + 1e-12f;
  st = (cv - lo) / (float)(D - 1);
}

template <int D, int H, int W>
__global__ void range_kernel(const float* __restrict__ prev_d,
                             const float* __restrict__ prev_v,
                             float2* __restrict__ rng) {
  int pix = blockIdx.x * 256 + threadIdx.x;
  if (pix >= H * W) return;
  float b, s;
  stage2_range<D, H, W>(prev_d, prev_v, pix / W, pix % W, b, s);
  rng[pix] = make_float2(b, s);
}

// One thread computes 8 channels of the variance volume at (d, gy, gx).
// Output GROUP-SPLIT layout: var[((d*C8 + cg)*H*W + pix)*8ch].
template <int C, int DTOT, int H, int W, bool STAGE2>
__launch_bounds__(256)
__global__ void gather_var_kernel(const _Float16* __restrict__ feats,
                                  const float* __restrict__ mats,
                                  const float* __restrict__ dpar,
                                  const float2* __restrict__ rng,
                                  _Float16* __restrict__ var_out) {
  constexpr int C8 = C / 8;
  const int idx = blockIdx.x * 256 + threadIdx.x;
  if (idx >= DTOT * H * W * C8) return;
  const int cg = idx % C8;
  const int t = idx / C8;
  const int gx = t % W;
  const int t2 = t / W;
  const int gy = t2 % H;
  const int d = t2 / H;
  const int pix = gy * W + gx;

  float base, st;
  if constexpr (STAGE2) {
    float2 r = rng[pix];
    base = r.x;
    st = r.y;
  } else {
    base = dpar[0];
    st = dpar[1];
  }
  const float dep = base + (float)d * st;

  const half8_t* fp = (const half8_t*)feats;
  half8_t rh = fp[(size_t)pix * C8 + cg];
  float s[8], q[8];
#pragma unroll
  for (int j = 0; j < 8; ++j) {
    float x = (float)rh[j];
    s[j] = x;
    q[j] = x * x;
  }

#pragma unroll
  for (int v = 0; v < 2; ++v) {
    const float* M = mats + v * 12;
    float fx = (float)gx, fy = (float)gy;
    float X = (M[0] * fx + M[1] * fy + M[2]) * dep + M[9];
    float Y = (M[3] * fx + M[4] * fy + M[5]) * dep + M[10];
    float Z = (M[6] * fx + M[7] * fy + M[8]) * dep + M[11];
    float inv = 1.0f / Z;
    float xz = X * inv, yz = Y * inv;
    float gxn = xz * (2.0f / (float)(W - 1)) - 1.0f;
    float gyn = yz * (2.0f / (float)(H - 1)) - 1.0f;
    float ix = ((gxn + 1.0f) * (float)W - 1.0f) * 0.5f;
    float iy = ((gyn + 1.0f) * (float)H - 1.0f) * 0.5f;
    float x0f = floorf(ix), y0f = floorf(iy);
    float wx = ix - x0f, wy = iy - y0f;
    float x1f = x0f + 1.0f, y1f = y0f + 1.0f;
    bool vx0 = (x0f >= 0.0f) && (x0f <= (float)(W - 1));
    bool vx1 = (x1f >= 0.0f) && (x1f <= (float)(W - 1));
    bool vy0 = (y0f >= 0.0f) && (y0f <= (float)(H - 1));
    bool vy1 = (y1f >= 0.0f) && (y1f <= (float)(H - 1));
    int xc0 = (int)fminf(fmaxf(x0f, 0.0f), (float)(W - 1));
    int xc1 = (int)fminf(fmaxf(x1f, 0.0f), (float)(W - 1));
    int yc0 = (int)fminf(fmaxf(y0f, 0.0f), (float)(H - 1));
    int yc1 = (int)fminf(fmaxf(y1f, 0.0f), (float)(H - 1));
    float wxm = 1.0f - wx, wym = 1.0f - wy;
    float a00 = (vx0 && vy0) ? wxm * wym : 0.0f;
    float a10 = (vx1 && vy0) ? wx * wym : 0.0f;
    float a01 = (vx0 && vy1) ? wxm * wy : 0.0f;
    float a11 = (vx1 && vy1) ? wx * wy : 0.0f;
    const size_t vb = (size_t)(v + 1) * H * W * C8 + cg;
    half8_t p00 = fp[vb + (size_t)(yc0 * W + xc0) * C8];
    half8_t p10 = fp[vb + (size_t)(yc0 * W + xc1) * C8];
    half8_t p01 = fp[vb + (size_t)(yc1 * W + xc0) * C8];
    half8_t p11 = fp[vb + (size_t)(yc1 * W + xc1) * C8];
#pragma unroll
    for (int j = 0; j < 8; ++j) {
      float g = a00 * (float)p00[j] + a10 * (float)p10[j] +
                a01 * (float)p01[j] + a11 * (float)p11[j];
      s[j] += g;
      q[j] += g * g;
    }
  }
  half8_t o;
#pragma unroll
  for (int j = 0; j < 8; ++j) {
    float m = s[j] * (1.0f / 3.0f);
    o[j] = (_Float16)(q[j] * (1.0f / 3.0f) - m * m);
  }
  *(half8_t*)(var_out + ((size_t)(d * C8 + cg) * (H * W) + pix) * 8) = o;
}

// 3x3x3 conv over fp16 group-split var volume -> fp32 cost volume [d][pix].
// Per-wave barrier-free staging; weights preloaded into VGPRs (loop-invariant,
// eliminates all in-loop weight loads); depth-3 per-wave pipeline.
template <int C, int DTOT, int DC, int H, int W>
__launch_bounds__(256)
__global__ void conv_cost_kernel(const uint4* __restrict__ var_in,  // [d][C/8][HW] 8-fp16 recs
                                 const _Float16* __restrict__ w2h,  // [tap][kd][C]
                                 const float* __restrict__ bconv,
                                 float* __restrict__ g_cost) {
  constexpr int TH = 8, TW = 8, WB = 10, HALO = 100, NPX = 64;
  constexpr int NS = DC + 2;
  constexpr int CPG = C / 4;  // channels per wave-group (8 for C=32, 4 for C=16)
  constexpr int HW = H * W;
  constexpr int C8 = C / 8;
  constexpr int BYTES_PER_PX = (CPG == 8) ? 16 : 8;

  __shared__ __align__(16) unsigned char s_raw[4 * 2 * HALO * BYTES_PER_PX];
  __shared__ float s_cost[DC * NPX];

  uint4* s_wv4 = (uint4*)s_raw;  // [(grp*2+b)*HALO + i]  (CPG==8)
  uint2* s_wv2 = (uint2*)s_raw;  // [(grp*2+b)*HALO + i]  (CPG==4)

  const int tid = threadIdx.x;
  const int lane = tid & 63;
  const int grp = tid >> 6;
  const int h0 = blockIdx.y * TH;
  const int w0 = blockIdx.x * TW;
  const int d0 = blockIdx.z * DC;

  {
    float bias = bconv[0];
    for (int i = tid; i < DC * NPX; i += 256) s_cost[i] = bias;
  }
  __syncthreads();  // s_cost init visible before any wave's atomics

  // preload loop-invariant weights into registers (27 vectors per wave-group)
  const _Float16* __restrict__ wg = w2h + __builtin_amdgcn_readfirstlane(grp * CPG);
  U4H wr4[27];
  U2H wr2[27];
  if constexpr (CPG == 8) {
#pragma unroll
    for (int i = 0; i < 27; ++i) wr4[i].u = *(const uint4*)(wg + i * C);
  } else {
#pragma unroll
    for (int i = 0; i < 27; ++i) wr2[i].u = *(const uint2*)(wg + i * C);
  }

  // per-lane staging items (2 per lane cover HALO=100)
  int gidx[2], ldi[2];
  bool act[2], gval[2];
#pragma unroll
  for (int k = 0; k < 2; ++k) {
    int i = lane + k * 64;
    act[k] = (i < HALO);
    int hy = i / WB, hx = i - (i / WB) * WB;
    int gy = h0 + hy - 1, gx = w0 + hx - 1;
    gval[k] = act[k] && gy >= 0 && gy < H && gx >= 0 && gx < W;
    gidx[k] = gval[k] ? (gy * W + gx) : 0;
    ldi[k] = i;
  }

  uint4 pf4[3][2];
  uint2 pf2[3][2];
  auto prefetch = [&](int slot, int ds) {
    const bool dv = (ds >= 0) && (ds < DTOT);
#pragma unroll
    for (int k = 0; k < 2; ++k) {
      if constexpr (CPG == 8) {
        uint4 r = make_uint4(0u, 0u, 0u, 0u);
        if (dv && gval[k]) r = var_in[(size_t)(ds * C8 + grp) * HW + gidx[k]];
        pf4[slot][k] = r;
      } else {
        uint2 r = make_uint2(0u, 0u);
        if (dv && gval[k])
          r = ((const uint2*)var_in)[((size_t)(ds * C8 + (grp >> 1)) * HW + gidx[k]) * 2 +
                                     (grp & 1)];
        pf2[slot][k] = r;
      }
    }
  };
  auto commit = [&](int slot, int b) {
#pragma unroll
    for (int k = 0; k < 2; ++k)
      if (act[k]) {
        if constexpr (CPG == 8) s_wv4[(grp * 2 + b) * HALO + ldi[k]] = pf4[slot][k];
        else s_wv2[(grp * 2 + b) * HALO + ldi[k]] = pf2[slot][k];
      }
  };

  const int opx = lane;
  const int py = opx >> 3, pxx = opx & 7;

  auto conv_accum = [&](int ds, int b) {
    float a0 = 0.f, a1 = 0.f, a2 = 0.f;  // kd = 0,1,2
#pragma unroll
    for (int t = 0; t < 9; ++t) {
      const int kh = t / 3, kw = t - 3 * kh;
      const int hp = (py + kh) * WB + (pxx + kw);
      if constexpr (CPG == 8) {
        U4H v;
        v.u = s_wv4[(grp * 2 + b) * HALO + hp];
#pragma unroll
        for (int kd = 0; kd < 3; ++kd) {
          const U4H& w = wr4[t * 3 + kd];
          float acc = 0.f;
#pragma unroll
          for (int j = 0; j < 4; ++j) acc = fdot2f(v.h[j], w.h[j], acc);
          if (kd == 0) a0 += acc;
          else if (kd == 1) a1 += acc;
          else a2 += acc;
        }
      } else {
        U2H v;
        v.u = s_wv2[(grp * 2 + b) * HALO + hp];
#pragma unroll
        for (int kd = 0; kd < 3; ++kd) {
          const U2H& w = wr2[t * 3 + kd];
          float acc = 0.f;
#pragma unroll
          for (int j = 0; j < 2; ++j) acc = fdot2f(v.h[j], w.h[j], acc);
          if (kd == 0) a0 += acc;
          else if (kd == 1) a1 += acc;
          else a2 += acc;
        }
      }
    }
    int t0 = ds + 1 - d0;
    int t1 = ds - d0;
    int t2 = ds - 1 - d0;
    if (t0 >= 0 && t0 < DC) atomicAdd(&s_cost[t0 * NPX + opx], a0);
    if (t1 >= 0 && t1 < DC) atomicAdd(&s_cost[t1 * NPX + opx], a1);
    if (t2 >= 0 && t2 < DC) atomicAdd(&s_cost[t2 * NPX + opx], a2);
  };

  // per-wave depth-3 pipeline, no barriers (buffers are wave-private).
  // slot (s)%3 holds slice d0-1+s; LDS buffer s&1 holds slice s's data.
  prefetch(0, d0 - 1);
  commit(0, 0);
  prefetch(1, d0);
  prefetch(2, d0 + 1);
  for (int s = 0; s < NS; ++s) {
    if (s + 3 < NS) prefetch(s % 3, d0 - 1 + s + 3);  // 2 intervals of cover
    conv_accum(d0 - 1 + s, s & 1);
    if (s + 1 < NS) commit((s + 1) % 3, (s + 1) & 1);
  }
  __syncthreads();  // all waves' atomics done

  for (int i = tid; i < DC * NPX; i += 256) {
    int dd = i / NPX, o = i - dd * NPX;
    int oy = o / TW, ox = o - oy * TW;
    g_cost[(size_t)(d0 + dd) * (H * W) + (h0 + oy) * W + (w0 + ox)] = s_cost[i];
  }
}

template <int D, int H, int W, bool STAGE2>
__global__ void epilogue_kernel(const float* __restrict__ g_cost,
                                const float* __restrict__ dpar,
                                const float2* __restrict__ rng,
                                float* __restrict__ out_d,
                                float* __restrict__ out_c,
                                float* __restrict__ out_v) {
  int pix = blockIdx.x * 256 + threadIdx.x;
  if (pix >= H * W) return;
  float base, st;
  if constexpr (STAGE2) {
    float2 r = rng[pix];
    base = r.x;
    st = r.y;
  } else {
    base = dpar[0];
    st = dpar[1];
  }
  float c[D];
#pragma unroll
  for (int dd = 0; dd < D; ++dd) c[dd] = g_cost[(size_t)dd * (H * W) + pix];
  float mx = -3.0e38f;
#pragma unroll
  for (int dd = 0; dd < D; ++dd) mx = fmaxf(mx, c[dd]);
  float se = 0.f;
#pragma unroll
  for (int dd = 0; dd < D; ++dd) {
    float e = expf(c[dd] - mx);
    c[dd] = e;
    se += e;
  }
  float depth = 0.f, dif = 0.f;
#pragma unroll
  for (int dd = 0; dd < D; ++dd) {
    float p = c[dd] / se;
    c[dd] = p;
    depth += p * (base + (float)dd * st);
    dif += p * (float)dd;
  }
  int di = (int)dif;
  di = min(max(di, 0), D - 1);
  float conf = 0.f;
#pragma unroll
  for (int dd = 0; dd < D; ++dd)
    if (dd >= di - 1 && dd <= di + 2) conf += c[dd];
  float ev = 0.f;
#pragma unroll
  for (int dd = 0; dd < D; ++dd) {
    float sv = base + (float)dd * st - depth;
    ev += sv * sv * c[dd];
  }
  ev = 1.5f * sqrtf(ev);
  out_d[pix] = depth;
  out_c[pix] = conf;
  out_v[pix] = ev;
}

// -------------------- fused fp32 fallback (small-ws tiers) --------------------

template <int C, int DTOT, int DC, int TH, int TW, int H, int W, bool STAGE2, bool EPI>
__launch_bounds__(256)
__global__ void cost_kernel(const float* __restrict__ feats,
                            const float* __restrict__ wconv,
                            const float* __restrict__ bconv,
                            const float* __restrict__ mats,
                            const float* __restrict__ dpar,
                            const float* __restrict__ prev_d,
                            const float* __restrict__ prev_v,
                            float* __restrict__ g_cost,
                            float* __restrict__ out_d,
                            float* __restrict__ out_c,
                            float* __restrict__ out_v) {
  constexpr int HB = TH + 2, WB = TW + 2, HALO = HB * WB, NPX = TH * TW;
  constexpr int HP = HALO + 1;
  constexpr int CG = C / 4;
  constexpr int NS = DC + 2;
  constexpr int VITEMS = HALO * C;

  __shared__ float s_var[2][C * HP];
  __shared__ float s_cost[DC * NPX];
  __shared__ float s_w[C * 27];
  __shared__ float s_rx[2][HALO], s_ry[2][HALO], s_rz[2][HALO];
  __shared__ float s_cw[2][2][4][HALO];
  __shared__ int s_ci[2][2][4][HALO];
  __shared__ int s_gidx[HALO];
  __shared__ float s_dbase[HALO], s_dstep[HALO];
  __shared__ unsigned char s_inb[HALO];

  const int tid = threadIdx.x;
  const int h0 = blockIdx.y * TH;
  const int w0 = blockIdx.x * TW;
  const int d0 = EPI ? 0 : blockIdx.z * DC;

  for (int i = tid; i < C * 27; i += 256) s_w[i] = wconv[i];

  for (int i = tid; i < HALO; i += 256) {
    int hy = i / WB, hx = i - hy * WB;
    int gy = h0 + hy - 1, gx = w0 + hx - 1;
    bool inb = (gy >= 0) && (gy < H) && (gx >= 0) && (gx < W);
    s_inb[i] = inb ? 1 : 0;
    s_gidx[i] = inb ? (gy * W + gx) : 0;
    float fx = (float)gx, fy = (float)gy;
#pragma unroll
    for (int v = 0; v < 2; ++v) {
      const float* M = mats + v * 12;
      s_rx[v][i] = M[0] * fx + M[1] * fy + M[2];
      s_ry[v][i] = M[3] * fx + M[4] * fy + M[5];
      s_rz[v][i] = M[6] * fx + M[7] * fy + M[8];
    }
    if constexpr (STAGE2) {
      float b, stp;
      stage2_range<DTOT, H, W>(prev_d, prev_v, gy, gx, b, stp);
      s_dbase[i] = b;
      s_dstep[i] = stp;
    } else {
      s_dbase[i] = dpar[0];
      s_dstep[i] = dpar[1];
    }
  }
  {
    float bias = bconv[0];
    for (int i = tid; i < DC * NPX; i += 256) s_cost[i] = bias;
  }
  __syncthreads();

  auto do_coords = [&](int ds, int b, int i) {
    int v = (i >= HALO) ? 1 : 0;
    int px = i - v * HALO;
    float dep = s_dbase[px] + (float)ds * s_dstep[px];
    const float* M = mats + v * 12;
    float X = s_rx[v][px] * dep + M[9];
    float Y = s_ry[v][px] * dep + M[10];
    float Z = s_rz[v][px] * dep + M[11];
    float inv = 1.0f / Z;
    float xz = X * inv, yz = Y * inv;
    float gxn = xz * (2.0f / (float)(W - 1)) - 1.0f;
    float gyn = yz * (2.0f / (float)(H - 1)) - 1.0f;
    float ix = ((gxn + 1.0f) * (float)W - 1.0f) * 0.5f;
    float iy = ((gyn + 1.0f) * (float)H - 1.0f) * 0.5f;
    float x0f = floorf(ix), y0f = floorf(iy);
    float wx = ix - x0f, wy = iy - y0f;
    float x1f = x0f + 1.0f, y1f = y0f + 1.0f;
    bool vx0 = (x0f >= 0.0f) && (x0f <= (float)(W - 1));
    bool vx1 = (x1f >= 0.0f) && (x1f <= (float)(W - 1));
    bool vy0 = (y0f >= 0.0f) && (y0f <= (float)(H - 1));
    bool vy1 = (y1f >= 0.0f) && (y1f <= (float)(H - 1));
    int xc0 = (int)fminf(fmaxf(x0f, 0.0f), (float)(W - 1));
    int xc1 = (int)fminf(fmaxf(x1f, 0.0f), (float)(W - 1));
    int yc0 = (int)fminf(fmaxf(y0f, 0.0f), (float)(H - 1));
    int yc1 = (int)fminf(fmaxf(y1f, 0.0f), (float)(H - 1));
    s_ci[b][v][0][px] = yc0 * W + xc0;
    s_ci[b][v][1][px] = yc0 * W + xc1;
    s_ci[b][v][2][px] = yc1 * W + xc0;
    s_ci[b][v][3][px] = yc1 * W + xc1;
    float wxm = 1.0f - wx, wym = 1.0f - wy;
    s_cw[b][v][0][px] = (vx0 && vy0) ? wxm * wym : 0.0f;
    s_cw[b][v][1][px] = (vx1 && vy0) ? wx * wym : 0.0f;
    s_cw[b][v][2][px] = (vx0 && vy1) ? wxm * wy : 0.0f;
    s_cw[b][v][3][px] = (vx1 && vy1) ? wx * wy : 0.0f;
  };

  auto do_variance = [&](int b, int b2, int i) {
    int c = i / HALO, px = i - (i / HALO) * HALO;
    float var = 0.f;
    if (s_inb[px]) {
      const float* f0 = feats + (size_t)c * (H * W);
      float rr = f0[s_gidx[px]];
      float sum = rr, ssq = rr * rr;
#pragma unroll
      for (int v = 0; v < 2; ++v) {
        const float* fv = feats + ((size_t)(v + 1) * C + c) * (H * W);
        float val = s_cw[b][v][0][px] * fv[s_ci[b][v][0][px]] +
                    s_cw[b][v][1][px] * fv[s_ci[b][v][1][px]] +
                    s_cw[b][v][2][px] * fv[s_ci[b][v][2][px]] +
                    s_cw[b][v][3][px] * fv[s_ci[b][v][3][px]];
        sum += val;
        ssq += val * val;
      }
      float m = sum / 3.0f;
      var = ssq / 3.0f - m * m;
    }
    s_var[b2][c * HP + px] = var;
  };

  auto conv_accum = [&](int ds, int sb) {
    for (int i = tid; i < NPX * 4; i += 256) {
      int grp = i / NPX, opx = i - grp * NPX;
      int py = opx / TW, pxx = opx - py * TW;
      float a0 = 0.f, a1 = 0.f, a2 = 0.f;
      int cbase = grp * CG;
#pragma unroll
      for (int kh = 0; kh < 3; ++kh) {
#pragma unroll
        for (int kw = 0; kw < 3; ++kw) {
          int hp = (py + kh) * WB + (pxx + kw);
#pragma unroll
          for (int cc = 0; cc < CG; ++cc) {
            int c = cbase + cc;
            float vv = s_var[sb][c * HP + hp];
            const float* wp = s_w + c * 27 + kh * 3 + kw;
            a0 += vv * wp[0];
            a1 += vv * wp[9];
            a2 += vv * wp[18];
          }
        }
      }
      int t0 = ds + 1 - d0;
      int t1 = ds - d0;
      int t2 = ds - 1 - d0;
      if (t0 >= 0 && t0 < DC) atomicAdd(&s_cost[t0 * NPX + opx], a0);
      if (t1 >= 0 && t1 < DC) atomicAdd(&s_cost[t1 * NPX + opx], a1);
      if (t2 >= 0 && t2 < DC) atomicAdd(&s_cost[t2 * NPX + opx], a2);
    }
  };

  {
    int ds0 = d0 - 1;
    if (ds0 >= 0 && ds0 < DTOT)
      for (int i = tid; i < 2 * HALO; i += 256) do_coords(ds0, 0, i);
  }
  __syncthreads();

  for (int s = 0; s <= NS; ++s) {
    const int ds = d0 - 1 + s;
    const bool val_cur = (s < NS) && (ds >= 0) && (ds < DTOT);
    const bool val_next = (s + 1 < NS) && (ds + 1 >= 0) && (ds + 1 < DTOT);
    const bool val_prev = (s >= 1) && (ds - 1 >= 0) && (ds - 1 < DTOT);
    if (val_cur)
      for (int i = tid; i < VITEMS; i += 256) do_variance(s & 1, s & 1, i);
    if (val_next)
      for (int i = tid; i < 2 * HALO; i += 256) do_coords(ds + 1, (s + 1) & 1, i);
    if (val_prev) conv_accum(ds - 1, (s - 1) & 1);
    __syncthreads();
  }

  if constexpr (!EPI) {
    for (int i = tid; i < DC * NPX; i += 256) {
      int dd = i / NPX, opx = i - dd * NPX;
      int py = opx / TW, pxx = opx - py * TW;
      g_cost[(size_t)(d0 + dd) * (H * W) + (h0 + py) * W + (w0 + pxx)] = s_cost[i];
    }
  } else if (tid < NPX) {
    const int opx = tid;
    const int py = opx / TW, pxx = opx - py * TW;
    const int hp = (py + 1) * WB + (pxx + 1);
    const float base = s_dbase[hp], st = s_dstep[hp];
    float mx = -3.0e38f;
    for (int dd = 0; dd < DTOT; ++dd) mx = fmaxf(mx, s_cost[dd * NPX + opx]);
    float se = 0.f;
    for (int dd = 0; dd < DTOT; ++dd) {
      float e = expf(s_cost[dd * NPX + opx] - mx);
      s_cost[dd * NPX + opx] = e;
      se += e;
    }
    float depth = 0.f, dif = 0.f;
    for (int dd = 0; dd < DTOT; ++dd) {
      float p = s_cost[dd * NPX + opx] / se;
      s_cost[dd * NPX + opx] = p;
      depth += p * (base + (float)dd * st);
      dif += p * (float)dd;
    }
    int di = (int)dif;
    di = min(max(di, 0), DTOT - 1);
    float conf = 0.f;
    for (int k = di - 1; k <= di + 2; ++k)
      if (k >= 0 && k < DTOT) conf += s_cost[k * NPX + opx];
    float ev = 0.f;
    for (int dd = 0; dd < DTOT; ++dd) {
      float sv = base + (float)dd * st - depth;
      ev += sv * sv * s_cost[dd * NPX + opx];
    }
    ev = 1.5f * sqrtf(ev);
    int gy = h0 + py, gx = w0 + pxx;
    out_d[gy * W + gx] = depth;
    out_c[gy * W + gx] = conf;
    out_v[gy * W + gx] = ev;
  }
}

extern "C" void kernel_launch(void* const* d_in, const int* in_sizes, int n_in,
                              void* d_out, int out_size, void* d_ws, size_t ws_size,
                              hipStream_t stream) {
  const float* feats1 = (const float*)d_in[0];
  const float* feats2 = (const float*)d_in[1];
  const float* proj1 = (const float*)d_in[2];
  const float* proj2 = (const float*)d_in[3];
  const float* depthv = (const float*)d_in[4];
  const float* w1 = (const float*)d_in[6];
  const float* b1 = (const float*)d_in[7];
  const float* w2 = (const float*)d_in[8];
  const float* b2 = (const float*)d_in[9];
  float* out = (float*)d_out;
  float* ws = (float*)d_ws;

  const int nd = in_sizes[4];
  const size_t F1 = (size_t)3 * 32 * 128 * 160;     // elements
  const size_t F2 = (size_t)3 * 16 * 256 * 320;
  const size_t COST1 = (size_t)48 * 128 * 160;
  const size_t COST2 = (size_t)8 * 256 * 320;
  const size_t VAR1 = (size_t)48 * 128 * 160 * 32;  // fp16 elements
  const size_t VAR2 = (size_t)8 * 256 * 320 * 16;
  const size_t RNG2 = (size_t)2 * 256 * 320;
  const size_t HDR = 1408;
  const size_t HUGE_FLOATS =
      HDR + COST1 + COST2 + F1 / 2 + F2 / 2 + VAR1 / 2 + VAR2 / 2 + RNG2;
  const bool huge = ws_size >= HUGE_FLOATS * sizeof(float);
  const bool mid = ws_size >= (64 + COST1) * sizeof(float);

  float* d1 = out;
  float* c1 = out + 20480;
  float* v1 = out + 40960;
  float* d2 = out + 61440;
  float* c2 = out + 143360;
  float* v2 = out + 225280;

  dim3 g1c(160 / 8, 128 / 8, 6), g1f(160 / 8, 128 / 8, 1), g2(320 / 8, 256 / 8, 1);

  if (huge) {
    _Float16* w2a = (_Float16*)(ws + 64);   // 864 fp16
    _Float16* w2b = (_Float16*)(ws + 512);  // 432 fp16
    float* cost1 = ws + HDR;
    float* cost2 = cost1 + COST1;
    _Float16* f1t = (_Float16*)(cost2 + COST2);
    _Float16* f2t = (_Float16*)(cost2 + COST2 + F1 / 2);
    _Float16* var1 = (_Float16*)(cost2 + COST2 + F1 / 2 + F2 / 2);
    _Float16* var2 = (_Float16*)(cost2 + COST2 + F1 / 2 + F2 / 2 + VAR1 / 2);
    float2* rng2 = (float2*)(cost2 + COST2 + F1 / 2 + F2 / 2 + VAR1 / 2 + VAR2 / 2);
    setup_mats_kernel<<<1, 256, 0, stream>>>(proj1, proj2, depthv, nd, ws, w1, w2, w2a, w2b);
    transpose_f16_kernel<32, 128, 160><<<dim3(5, 128, 3), 256, 0, stream>>>(feats1, f1t);
    transpose_f16_kernel<16, 256, 320><<<dim3(10, 256, 3), 256, 0, stream>>>(feats2, f2t);
    // stage 1
    gather_var_kernel<32, 48, 128, 160, false>
        <<<(int)((VAR1 / 8 + 255) / 256), 256, 0, stream>>>(f1t, ws, ws + 48, nullptr, var1);
    conv_cost_kernel<32, 48, 8, 128, 160><<<g1c, 256, 0, stream>>>(
        (const uint4*)var1, w2a, b1, cost1);
    epilogue_kernel<48, 128, 160, false><<<80, 256, 0, stream>>>(
        cost1, ws + 48, nullptr, d1, c1, v1);
    // stage 2
    range_kernel<8, 256, 320><<<320, 256, 0, stream>>>(d1, v1, rng2);
    gather_var_kernel<16, 8, 256, 320, true>
        <<<(int)((VAR2 / 8 + 255) / 256), 256, 0, stream>>>(f2t, ws + 24, ws + 48, rng2, var2);
    conv_cost_kernel<16, 8, 8, 256, 320><<<dim3(40, 32, 1), 256, 0, stream>>>(
        (const uint4*)var2, w2b, b2, cost2);
    epilogue_kernel<8, 256, 320, true><<<320, 256, 0, stream>>>(
        cost2, ws + 48, rng2, d2, c2, v2);
  } else if (mid) {
    float* cost1 = ws + 64;
    setup_mats_kernel<<<1, 256, 0, stream>>>(proj1, proj2, depthv, nd, ws, w1, w2,
                                             nullptr, nullptr);
    cost_kernel<32, 48, 8, 8, 8, 128, 160, false, false><<<g1c, 256, 0, stream>>>(
        feats1, w1, b1, ws, ws + 48, nullptr, nullptr, cost1, nullptr, nullptr, nullptr);
    epilogue_kernel<48, 128, 160, false><<<80, 256, 0, stream>>>(
        cost1, ws + 48, nullptr, d1, c1, v1);
    cost_kernel<16, 8, 8, 8, 8, 256, 320, true, true><<<g2, 256, 0, stream>>>(
        feats2, w2, b2, ws + 24, ws + 48, d1, v1, nullptr, d2, c2, v2);
  } else {
    setup_mats_kernel<<<1, 256, 0, stream>>>(proj1, proj2, depthv, nd, ws, w1, w2,
                                             nullptr, nullptr);
    cost_kernel<32, 48, 48, 8, 8, 128, 160, false, true><<<g1f, 256, 0, stream>>>(
        feats1, w1, b1, ws, ws + 48, nullptr, nullptr, nullptr, d1, c1, v1);
    cost_kernel<16, 8, 8, 8, 8, 256, 320, true, true><<<g2, 256, 0, stream>>>(
        feats2, w2, b2, ws + 24, ws + 48, d1, v1, nullptr, d2, c2, v2);
  }
}

// Round 12
// 223.721 us; speedup vs baseline: 1.3594x; 1.3594x over previous
//
#include <hip/hip_runtime.h>
#include <math.h>

// ---------------------------------------------------------------------------
// CoarseMVSNet, de-fused fp16 pipeline (R12):
//   conv_cost_kernel RESTRUCTURED (R11 post-mortem: uniform weight loads are
//   scalar; 27 uint4 need 108 SGPRs > budget so the compiler rematerializes
//   them per interval regardless of source-level hoisting; the slice-loop
//   interleaves s_load+ds_read on the in-order lgkm counter = serialization).
//   New shape: stage ALL NS slices of the wave's channel group to LDS up
//   front (one big MLP burst), weights copied to wave-private LDS once, then
//   TAPS-OUTER / SLICES-INNER with register accumulators accA/B/C[NS];
//   zero atomics (per-group partials + one barrier + 4-way reduce).
// __launch_bounds__(256) ONLY (R2: (256,4) forced VGPR->64, 4.2 GB spill).
// ---------------------------------------------------------------------------

typedef _Float16 half2_t __attribute__((ext_vector_type(2)));
typedef _Float16 half8_t __attribute__((ext_vector_type(8)));

union U4H { uint4 u; half2_t h[4]; };
union U2H { uint2 u; half2_t h[2]; };

static __device__ inline float fdot2f(half2_t a, half2_t b, float c) {
#if __has_builtin(__builtin_amdgcn_fdot2)
  return __builtin_amdgcn_fdot2(a, b, c, false);
#else
  return c + (float)a[0] * (float)b[0] + (float)a[1] * (float)b[1];
#endif
}

// mats (thread 0) + fp16 weight relayout w[c][kd][kh][kw] -> w2h[(t*3+kd)][c]
__global__ void setup_mats_kernel(const float* __restrict__ proj1,
                                  const float* __restrict__ proj2,
                                  const float* __restrict__ depthv, int nd,
                                  float* __restrict__ ws,
                                  const float* __restrict__ w1,
                                  const float* __restrict__ w2,
                                  _Float16* __restrict__ w2a,
                                  _Float16* __restrict__ w2b) {
  const int tid = threadIdx.x;
  if (w2a != nullptr) {
    for (int i = tid; i < 27 * 32; i += 256) {
      int c = i % 32, r = i / 32, kd = r % 3, t = r / 3;
      w2a[(t * 3 + kd) * 32 + c] = (_Float16)w1[c * 27 + kd * 9 + t];
    }
    for (int i = tid; i < 27 * 16; i += 256) {
      int c = i % 16, r = i / 16, kd = r % 3, t = r / 3;
      w2b[(t * 3 + kd) * 16 + c] = (_Float16)w2[c * 27 + kd * 9 + t];
    }
  }
  if (tid != 0) return;
  for (int s = 0; s < 2; ++s) {
    const float* P = s ? proj2 : proj1;  // (3,2,4,4) flat
    double comp[3][4][4];
    for (int v = 0; v < 3; ++v) {
      const float* E = P + v * 32;
      const float* K = P + v * 32 + 16;
      for (int r = 0; r < 3; ++r)
        for (int c = 0; c < 4; ++c) {
          double acc = 0.0;
          for (int k = 0; k < 3; ++k) acc += (double)K[r * 4 + k] * (double)E[k * 4 + c];
          comp[v][r][c] = acc;
        }
      for (int c = 0; c < 4; ++c) comp[v][3][c] = (double)E[12 + c];
    }
    double a[4][8];
    for (int r = 0; r < 4; ++r)
      for (int c = 0; c < 4; ++c) {
        a[r][c] = comp[0][r][c];
        a[r][4 + c] = (r == c) ? 1.0 : 0.0;
      }
    for (int col = 0; col < 4; ++col) {
      int piv = col;
      double best = fabs(a[col][col]);
      for (int r = col + 1; r < 4; ++r) {
        double t = fabs(a[r][col]);
        if (t > best) { best = t; piv = r; }
      }
      if (piv != col)
        for (int c = 0; c < 8; ++c) { double t = a[col][c]; a[col][c] = a[piv][c]; a[piv][c] = t; }
      double dv = a[col][col];
      for (int c = 0; c < 8; ++c) a[col][c] /= dv;
      for (int r = 0; r < 4; ++r)
        if (r != col) {
          double f = a[r][col];
          if (f != 0.0)
            for (int c = 0; c < 8; ++c) a[r][c] -= f * a[col][c];
        }
    }
    for (int v = 1; v < 3; ++v) {
      double Pm[3][4];
      for (int r = 0; r < 3; ++r)
        for (int c = 0; c < 4; ++c) {
          double acc = 0.0;
          for (int k = 0; k < 4; ++k) acc += comp[v][r][k] * a[k][4 + c];
          Pm[r][c] = acc;
        }
      float* o = ws + s * 24 + (v - 1) * 12;
      o[0] = (float)Pm[0][0]; o[1] = (float)Pm[0][1]; o[2] = (float)Pm[0][2];
      o[3] = (float)Pm[1][0]; o[4] = (float)Pm[1][1]; o[5] = (float)Pm[1][2];
      o[6] = (float)Pm[2][0]; o[7] = (float)Pm[2][1]; o[8] = (float)Pm[2][2];
      o[9] = (float)Pm[0][3]; o[10] = (float)Pm[1][3]; o[11] = (float)Pm[2][3];
    }
  }
  ws[48] = depthv[0];
  ws[49] = (depthv[nd - 1] - depthv[0]) / 47.0f;
}

// LDS-tiled coalesced transpose: fp32 (V,C,H,W) -> fp16 (V,H,W,C).
template <int C, int H, int W>
__global__ void transpose_f16_kernel(const float* __restrict__ in,
                                     _Float16* __restrict__ out) {
  __shared__ float s_t[C][33];
  const int v = blockIdx.z, h = blockIdx.y, w0 = blockIdx.x * 32;
  const int tid = threadIdx.x;
  for (int r = tid; r < C * 32; r += 256) {
    int c = r >> 5, w = r & 31;
    s_t[c][w] = in[((size_t)(v * C + c) * H + h) * W + w0 + w];
  }
  __syncthreads();
  for (int r = tid; r < 32 * C; r += 256) {
    int w = r / C, c = r - (r / C) * C;
    out[((size_t)(v * H + h) * W + w0 + w) * C + c] = (_Float16)s_t[c][w];
  }
}

// Per-pixel depth range for STAGE2: bilinear 2x upsample of d1/v1.
template <int D, int H, int W>
__device__ inline void stage2_range(const float* __restrict__ prev_d,
                                    const float* __restrict__ prev_v,
                                    int gy, int gx, float& base, float& st) {
  constexpr int SH = H / 2, SW = W / 2;
  float syf = 0.5f * (float)gy - 0.25f;
  float sxf = 0.5f * (float)gx - 0.25f;
  syf = fminf(fmaxf(syf, 0.0f), (float)(SH - 1));
  sxf = fminf(fmaxf(sxf, 0.0f), (float)(SW - 1));
  int sy0 = (int)syf, sx0 = (int)sxf;
  float fy2 = syf - (float)sy0, fx2 = sxf - (float)sx0;
  int sy1 = min(sy0 + 1, SH - 1), sx1 = min(sx0 + 1, SW - 1);
  int j00 = sy0 * SW + sx0, j01 = sy0 * SW + sx1;
  int j10 = sy1 * SW + sx0, j11 = sy1 * SW + sx1;
  float cd = (prev_d[j00] * (1.f - fx2) + prev_d[j01] * fx2) * (1.f - fy2) +
             (prev_d[j10] * (1.f - fx2) + prev_d[j11] * fx2) * fy2;
  float cv = (prev_v[j00] * (1.f - fx2) + prev_v[j01] * fx2) * (1.f - fy2) +
             (prev_v[j10] * (1.f - fx2) + prev_v[j11] * fx2) * fy2;
  float lo = -fminf(cd, cv);
  base = cd + lo + 1e-12f;
  st = (cv - lo) / (float)(D - 1);
}

template <int D, int H, int W>
__global__ void range_kernel(const float* __restrict__ prev_d,
                             const float* __restrict__ prev_v,
                             float2* __restrict__ rng) {
  int pix = blockIdx.x * 256 + threadIdx.x;
  if (pix >= H * W) return;
  float b, s;
  stage2_range<D, H, W>(prev_d, prev_v, pix / W, pix % W, b, s);
  rng[pix] = make_float2(b, s);
}

// One thread computes 8 channels of the variance volume at (d, gy, gx).
// Output GROUP-SPLIT layout: var[((d*C8 + cg)*H*W + pix)*8ch].
template <int C, int DTOT, int H, int W, bool STAGE2>
__launch_bounds__(256)
__global__ void gather_var_kernel(const _Float16* __restrict__ feats,
                                  const float* __restrict__ mats,
                                  const float* __restrict__ dpar,
                                  const float2* __restrict__ rng,
                                  _Float16* __restrict__ var_out) {
  constexpr int C8 = C / 8;
  const int idx = blockIdx.x * 256 + threadIdx.x;
  if (idx >= DTOT * H * W * C8) return;
  const int cg = idx % C8;
  const int t = idx / C8;
  const int gx = t % W;
  const int t2 = t / W;
  const int gy = t2 % H;
  const int d = t2 / H;
  const int pix = gy * W + gx;

  float base, st;
  if constexpr (STAGE2) {
    float2 r = rng[pix];
    base = r.x;
    st = r.y;
  } else {
    base = dpar[0];
    st = dpar[1];
  }
  const float dep = base + (float)d * st;

  const half8_t* fp = (const half8_t*)feats;
  half8_t rh = fp[(size_t)pix * C8 + cg];
  float s[8], q[8];
#pragma unroll
  for (int j = 0; j < 8; ++j) {
    float x = (float)rh[j];
    s[j] = x;
    q[j] = x * x;
  }

#pragma unroll
  for (int v = 0; v < 2; ++v) {
    const float* M = mats + v * 12;
    float fx = (float)gx, fy = (float)gy;
    float X = (M[0] * fx + M[1] * fy + M[2]) * dep + M[9];
    float Y = (M[3] * fx + M[4] * fy + M[5]) * dep + M[10];
    float Z = (M[6] * fx + M[7] * fy + M[8]) * dep + M[11];
    float inv = 1.0f / Z;
    float xz = X * inv, yz = Y * inv;
    float gxn = xz * (2.0f / (float)(W - 1)) - 1.0f;
    float gyn = yz * (2.0f / (float)(H - 1)) - 1.0f;
    float ix = ((gxn + 1.0f) * (float)W - 1.0f) * 0.5f;
    float iy = ((gyn + 1.0f) * (float)H - 1.0f) * 0.5f;
    float x0f = floorf(ix), y0f = floorf(iy);
    float wx = ix - x0f, wy = iy - y0f;
    float x1f = x0f + 1.0f, y1f = y0f + 1.0f;
    bool vx0 = (x0f >= 0.0f) && (x0f <= (float)(W - 1));
    bool vx1 = (x1f >= 0.0f) && (x1f <= (float)(W - 1));
    bool vy0 = (y0f >= 0.0f) && (y0f <= (float)(H - 1));
    bool vy1 = (y1f >= 0.0f) && (y1f <= (float)(H - 1));
    int xc0 = (int)fminf(fmaxf(x0f, 0.0f), (float)(W - 1));
    int xc1 = (int)fminf(fmaxf(x1f, 0.0f), (float)(W - 1));
    int yc0 = (int)fminf(fmaxf(y0f, 0.0f), (float)(H - 1));
    int yc1 = (int)fminf(fmaxf(y1f, 0.0f), (float)(H - 1));
    float wxm = 1.0f - wx, wym = 1.0f - wy;
    float a00 = (vx0 && vy0) ? wxm * wym : 0.0f;
    float a10 = (vx1 && vy0) ? wx * wym : 0.0f;
    float a01 = (vx0 && vy1) ? wxm * wy : 0.0f;
    float a11 = (vx1 && vy1) ? wx * wy : 0.0f;
    const size_t vb = (size_t)(v + 1) * H * W * C8 + cg;
    half8_t p00 = fp[vb + (size_t)(yc0 * W + xc0) * C8];
    half8_t p10 = fp[vb + (size_t)(yc0 * W + xc1) * C8];
    half8_t p01 = fp[vb + (size_t)(yc1 * W + xc0) * C8];
    half8_t p11 = fp[vb + (size_t)(yc1 * W + xc1) * C8];
#pragma unroll
    for (int j = 0; j < 8; ++j) {
      float g = a00 * (float)p00[j] + a10 * (float)p10[j] +
                a01 * (float)p01[j] + a11 * (float)p11[j];
      s[j] += g;
      q[j] += g * g;
    }
  }
  half8_t o;
#pragma unroll
  for (int j = 0; j < 8; ++j) {
    float m = s[j] * (1.0f / 3.0f);
    o[j] = (_Float16)(q[j] * (1.0f / 3.0f) - m * m);
  }
  *(half8_t*)(var_out + ((size_t)(d * C8 + cg) * (H * W) + pix) * 8) = o;
}

// 3x3x3 conv over fp16 group-split var volume -> fp32 cost volume [d][pix].
// Taps-outer / slices-inner. All NS slices of the wave's channel group staged
// to wave-private LDS up front (burst MLP); weights in wave-private LDS;
// register accumulators; no atomics; single barrier before writeout.
template <int C, int DTOT, int DC, int H, int W>
__launch_bounds__(256)
__global__ void conv_cost_kernel(const uint4* __restrict__ var_in,  // [d][C/8][HW] 8-fp16 recs
                                 const _Float16* __restrict__ w2h,  // [tap][kd][C]
                                 const float* __restrict__ bconv,
                                 float* __restrict__ g_cost) {
  constexpr int TH = 8, TW = 8, WB = 10, HALO = 100, NPX = 64;
  constexpr int NS = DC + 2;
  constexpr int CPG = C / 4;  // channels per wave (8 for C=32, 4 for C=16)
  constexpr int HW = H * W;
  constexpr int C8 = C / 8;
  constexpr int REC = (CPG == 8) ? 16 : 8;  // bytes per px per wave

  __shared__ __align__(16) unsigned char s_wv_raw[4 * NS * HALO * REC];
  __shared__ __align__(16) unsigned char s_wt_raw[4 * 27 * REC];
  __shared__ float s_part[4 * DC * NPX];

  uint4* s_wv4 = (uint4*)s_wv_raw;
  uint2* s_wv2 = (uint2*)s_wv_raw;
  uint4* s_wt4 = (uint4*)s_wt_raw;
  uint2* s_wt2 = (uint2*)s_wt_raw;

  const int tid = threadIdx.x;
  const int lane = tid & 63;
  const int grp = tid >> 6;
  const int h0 = blockIdx.y * TH;
  const int w0 = blockIdx.x * TW;
  const int d0 = blockIdx.z * DC;

  // weights for this wave's channel slice -> wave-private LDS (once)
  if (lane < 27) {
    if constexpr (CPG == 8)
      s_wt4[grp * 27 + lane] = *(const uint4*)(w2h + lane * C + grp * CPG);
    else
      s_wt2[grp * 27 + lane] = *(const uint2*)(w2h + lane * C + grp * CPG);
  }

  // per-lane staging geometry (2 items per lane cover HALO=100)
  int gidx[2], ldi[2];
  bool act[2], gval[2];
#pragma unroll
  for (int k = 0; k < 2; ++k) {
    int i = lane + k * 64;
    act[k] = (i < HALO);
    int hy = i / WB, hx = i - (i / WB) * WB;
    int gy = h0 + hy - 1, gx = w0 + hx - 1;
    gval[k] = act[k] && gy >= 0 && gy < H && gx >= 0 && gx < W;
    gidx[k] = gval[k] ? (gy * W + gx) : 0;
    ldi[k] = i;
  }

  // stage all NS slices (wave-private region, burst-issued loads, no barrier)
  if constexpr (CPG == 8) {
    uint4 pf[NS][2];
#pragma unroll
    for (int s = 0; s < NS; ++s) {
      int ds = d0 - 1 + s;
      bool dv = (ds >= 0) && (ds < DTOT);
#pragma unroll
      for (int k = 0; k < 2; ++k) {
        uint4 r = make_uint4(0u, 0u, 0u, 0u);
        if (dv && gval[k]) r = var_in[(size_t)(ds * C8 + grp) * HW + gidx[k]];
        pf[s][k] = r;
      }
    }
#pragma unroll
    for (int s = 0; s < NS; ++s)
#pragma unroll
      for (int k = 0; k < 2; ++k)
        if (act[k]) s_wv4[(grp * NS + s) * HALO + ldi[k]] = pf[s][k];
  } else {
    uint2 pf[NS][2];
#pragma unroll
    for (int s = 0; s < NS; ++s) {
      int ds = d0 - 1 + s;
      bool dv = (ds >= 0) && (ds < DTOT);
#pragma unroll
      for (int k = 0; k < 2; ++k) {
        uint2 r = make_uint2(0u, 0u);
        if (dv && gval[k])
          r = ((const uint2*)var_in)[((size_t)(ds * C8 + (grp >> 1)) * HW + gidx[k]) * 2 +
                                     (grp & 1)];
        pf[s][k] = r;
      }
    }
#pragma unroll
    for (int s = 0; s < NS; ++s)
#pragma unroll
      for (int k = 0; k < 2; ++k)
        if (act[k]) s_wv2[(grp * NS + s) * HALO + ldi[k]] = pf[s][k];
  }

  const int opx = lane;
  const int py = opx >> 3, pxx = opx & 7;

  float accA[NS], accB[NS], accC[NS];  // kd = 0,1,2 per staged slice
#pragma unroll
  for (int s = 0; s < NS; ++s) { accA[s] = 0.f; accB[s] = 0.f; accC[s] = 0.f; }

#pragma unroll
  for (int t = 0; t < 9; ++t) {
    const int kh = t / 3, kw = t - 3 * kh;
    const int hp = (py + kh) * WB + (pxx + kw);
    if constexpr (CPG == 8) {
      U4H w0v, w1v, w2v;
      w0v.u = s_wt4[grp * 27 + t * 3 + 0];
      w1v.u = s_wt4[grp * 27 + t * 3 + 1];
      w2v.u = s_wt4[grp * 27 + t * 3 + 2];
#pragma unroll
      for (int s = 0; s < NS; ++s) {
        U4H v;
        v.u = s_wv4[(grp * NS + s) * HALO + hp];
        float a = 0.f, b = 0.f, c = 0.f;
#pragma unroll
        for (int j = 0; j < 4; ++j) {
          a = fdot2f(v.h[j], w0v.h[j], a);
          b = fdot2f(v.h[j], w1v.h[j], b);
          c = fdot2f(v.h[j], w2v.h[j], c);
        }
        accA[s] += a;
        accB[s] += b;
        accC[s] += c;
      }
    } else {
      U2H w0v, w1v, w2v;
      w0v.u = s_wt2[grp * 27 + t * 3 + 0];
      w1v.u = s_wt2[grp * 27 + t * 3 + 1];
      w2v.u = s_wt2[grp * 27 + t * 3 + 2];
#pragma unroll
      for (int s = 0; s < NS; ++s) {
        U2H v;
        v.u = s_wv2[(grp * NS + s) * HALO + hp];
        float a = 0.f, b = 0.f, c = 0.f;
#pragma unroll
        for (int j = 0; j < 2; ++j) {
          a = fdot2f(v.h[j], w0v.h[j], a);
          b = fdot2f(v.h[j], w1v.h[j], b);
          c = fdot2f(v.h[j], w2v.h[j], c);
        }
        accA[s] += a;
        accB[s] += b;
        accC[s] += c;
      }
    }
  }

  // cost[j] (global slice d0+j) = x[d0+j-1]w0 + x[d0+j]w1 + x[d0+j+1]w2
  //                             = accA[j] + accB[j+1] + accC[j+2]
#pragma unroll
  for (int j = 0; j < DC; ++j)
    s_part[grp * (DC * NPX) + j * NPX + opx] = accA[j] + accB[j + 1] + accC[j + 2];
  __syncthreads();

  const float bias = bconv[0];
  for (int i = tid; i < DC * NPX; i += 256) {
    float v = bias + s_part[i] + s_part[DC * NPX + i] + s_part[2 * DC * NPX + i] +
              s_part[3 * DC * NPX + i];
    int dd = i / NPX, o = i - dd * NPX;
    int oy = o / TW, ox = o - oy * TW;
    g_cost[(size_t)(d0 + dd) * (H * W) + (h0 + oy) * W + (w0 + ox)] = v;
  }
}

template <int D, int H, int W, bool STAGE2>
__global__ void epilogue_kernel(const float* __restrict__ g_cost,
                                const float* __restrict__ dpar,
                                const float2* __restrict__ rng,
                                float* __restrict__ out_d,
                                float* __restrict__ out_c,
                                float* __restrict__ out_v) {
  int pix = blockIdx.x * 256 + threadIdx.x;
  if (pix >= H * W) return;
  float base, st;
  if constexpr (STAGE2) {
    float2 r = rng[pix];
    base = r.x;
    st = r.y;
  } else {
    base = dpar[0];
    st = dpar[1];
  }
  float c[D];
#pragma unroll
  for (int dd = 0; dd < D; ++dd) c[dd] = g_cost[(size_t)dd * (H * W) + pix];
  float mx = -3.0e38f;
#pragma unroll
  for (int dd = 0; dd < D; ++dd) mx = fmaxf(mx, c[dd]);
  float se = 0.f;
#pragma unroll
  for (int dd = 0; dd < D; ++dd) {
    float e = expf(c[dd] - mx);
    c[dd] = e;
    se += e;
  }
  float depth = 0.f, dif = 0.f;
#pragma unroll
  for (int dd = 0; dd < D; ++dd) {
    float p = c[dd] / se;
    c[dd] = p;
    depth += p * (base + (float)dd * st);
    dif += p * (float)dd;
  }
  int di = (int)dif;
  di = min(max(di, 0), D - 1);
  float conf = 0.f;
#pragma unroll
  for (int dd = 0; dd < D; ++dd)
    if (dd >= di - 1 && dd <= di + 2) conf += c[dd];
  float ev = 0.f;
#pragma unroll
  for (int dd = 0; dd < D; ++dd) {
    float sv = base + (float)dd * st - depth;
    ev += sv * sv * c[dd];
  }
  ev = 1.5f * sqrtf(ev);
  out_d[pix] = depth;
  out_c[pix] = conf;
  out_v[pix] = ev;
}

// -------------------- fused fp32 fallback (small-ws tiers) --------------------

template <int C, int DTOT, int DC, int TH, int TW, int H, int W, bool STAGE2, bool EPI>
__launch_bounds__(256)
__global__ void cost_kernel(const float* __restrict__ feats,
                            const float* __restrict__ wconv,
                            const float* __restrict__ bconv,
                            const float* __restrict__ mats,
                            const float* __restrict__ dpar,
                            const float* __restrict__ prev_d,
                            const float* __restrict__ prev_v,
                            float* __restrict__ g_cost,
                            float* __restrict__ out_d,
                            float* __restrict__ out_c,
                            float* __restrict__ out_v) {
  constexpr int HB = TH + 2, WB = TW + 2, HALO = HB * WB, NPX = TH * TW;
  constexpr int HP = HALO + 1;
  constexpr int CG = C / 4;
  constexpr int NS = DC + 2;
  constexpr int VITEMS = HALO * C;

  __shared__ float s_var[2][C * HP];
  __shared__ float s_cost[DC * NPX];
  __shared__ float s_w[C * 27];
  __shared__ float s_rx[2][HALO], s_ry[2][HALO], s_rz[2][HALO];
  __shared__ float s_cw[2][2][4][HALO];
  __shared__ int s_ci[2][2][4][HALO];
  __shared__ int s_gidx[HALO];
  __shared__ float s_dbase[HALO], s_dstep[HALO];
  __shared__ unsigned char s_inb[HALO];

  const int tid = threadIdx.x;
  const int h0 = blockIdx.y * TH;
  const int w0 = blockIdx.x * TW;
  const int d0 = EPI ? 0 : blockIdx.z * DC;

  for (int i = tid; i < C * 27; i += 256) s_w[i] = wconv[i];

  for (int i = tid; i < HALO; i += 256) {
    int hy = i / WB, hx = i - hy * WB;
    int gy = h0 + hy - 1, gx = w0 + hx - 1;
    bool inb = (gy >= 0) && (gy < H) && (gx >= 0) && (gx < W);
    s_inb[i] = inb ? 1 : 0;
    s_gidx[i] = inb ? (gy * W + gx) : 0;
    float fx = (float)gx, fy = (float)gy;
#pragma unroll
    for (int v = 0; v < 2; ++v) {
      const float* M = mats + v * 12;
      s_rx[v][i] = M[0] * fx + M[1] * fy + M[2];
      s_ry[v][i] = M[3] * fx + M[4] * fy + M[5];
      s_rz[v][i] = M[6] * fx + M[7] * fy + M[8];
    }
    if constexpr (STAGE2) {
      float b, stp;
      stage2_range<DTOT, H, W>(prev_d, prev_v, gy, gx, b, stp);
      s_dbase[i] = b;
      s_dstep[i] = stp;
    } else {
      s_dbase[i] = dpar[0];
      s_dstep[i] = dpar[1];
    }
  }
  {
    float bias = bconv[0];
    for (int i = tid; i < DC * NPX; i += 256) s_cost[i] = bias;
  }
  __syncthreads();

  auto do_coords = [&](int ds, int b, int i) {
    int v = (i >= HALO) ? 1 : 0;
    int px = i - v * HALO;
    float dep = s_dbase[px] + (float)ds * s_dstep[px];
    const float* M = mats + v * 12;
    float X = s_rx[v][px] * dep + M[9];
    float Y = s_ry[v][px] * dep + M[10];
    float Z = s_rz[v][px] * dep + M[11];
    float inv = 1.0f / Z;
    float xz = X * inv, yz = Y * inv;
    float gxn = xz * (2.0f / (float)(W - 1)) - 1.0f;
    float gyn = yz * (2.0f / (float)(H - 1)) - 1.0f;
    float ix = ((gxn + 1.0f) * (float)W - 1.0f) * 0.5f;
    float iy = ((gyn + 1.0f) * (float)H - 1.0f) * 0.5f;
    float x0f = floorf(ix), y0f = floorf(iy);
    float wx = ix - x0f, wy = iy - y0f;
    float x1f = x0f + 1.0f, y1f = y0f + 1.0f;
    bool vx0 = (x0f >= 0.0f) && (x0f <= (float)(W - 1));
    bool vx1 = (x1f >= 0.0f) && (x1f <= (float)(W - 1));
    bool vy0 = (y0f >= 0.0f) && (y0f <= (float)(H - 1));
    bool vy1 = (y1f >= 0.0f) && (y1f <= (float)(H - 1));
    int xc0 = (int)fminf(fmaxf(x0f, 0.0f), (float)(W - 1));
    int xc1 = (int)fminf(fmaxf(x1f, 0.0f), (float)(W - 1));
    int yc0 = (int)fminf(fmaxf(y0f, 0.0f), (float)(H - 1));
    int yc1 = (int)fminf(fmaxf(y1f, 0.0f), (float)(H - 1));
    s_ci[b][v][0][px] = yc0 * W + xc0;
    s_ci[b][v][1][px] = yc0 * W + xc1;
    s_ci[b][v][2][px] = yc1 * W + xc0;
    s_ci[b][v][3][px] = yc1 * W + xc1;
    float wxm = 1.0f - wx, wym = 1.0f - wy;
    s_cw[b][v][0][px] = (vx0 && vy0) ? wxm * wym : 0.0f;
    s_cw[b][v][1][px] = (vx1 && vy0) ? wx * wym : 0.0f;
    s_cw[b][v][2][px] = (vx0 && vy1) ? wxm * wy : 0.0f;
    s_cw[b][v][3][px] = (vx1 && vy1) ? wx * wy : 0.0f;
  };

  auto do_variance = [&](int b, int b2, int i) {
    int c = i / HALO, px = i - (i / HALO) * HALO;
    float var = 0.f;
    if (s_inb[px]) {
      const float* f0 = feats + (size_t)c * (H * W);
      float rr = f0[s_gidx[px]];
      float sum = rr, ssq = rr * rr;
#pragma unroll
      for (int v = 0; v < 2; ++v) {
        const float* fv = feats + ((size_t)(v + 1) * C + c) * (H * W);
        float val = s_cw[b][v][0][px] * fv[s_ci[b][v][0][px]] +
                    s_cw[b][v][1][px] * fv[s_ci[b][v][1][px]] +
                    s_cw[b][v][2][px] * fv[s_ci[b][v][2][px]] +
                    s_cw[b][v][3][px] * fv[s_ci[b][v][3][px]];
        sum += val;
        ssq += val * val;
      }
      float m = sum / 3.0f;
      var = ssq / 3.0f - m * m;
    }
    s_var[b2][c * HP + px] = var;
  };

  auto conv_accum = [&](int ds, int sb) {
    for (int i = tid; i < NPX * 4; i += 256) {
      int grp = i / NPX, opx = i - grp * NPX;
      int py = opx / TW, pxx = opx - py * TW;
      float a0 = 0.f, a1 = 0.f, a2 = 0.f;
      int cbase = grp * CG;
#pragma unroll
      for (int kh = 0; kh < 3; ++kh) {
#pragma unroll
        for (int kw = 0; kw < 3; ++kw) {
          int hp = (py + kh) * WB + (pxx + kw);
#pragma unroll
          for (int cc = 0; cc < CG; ++cc) {
            int c = cbase + cc;
            float vv = s_var[sb][c * HP + hp];
            const float* wp = s_w + c * 27 + kh * 3 + kw;
            a0 += vv * wp[0];
            a1 += vv * wp[9];
            a2 += vv * wp[18];
          }
        }
      }
      int t0 = ds + 1 - d0;
      int t1 = ds - d0;
      int t2 = ds - 1 - d0;
      if (t0 >= 0 && t0 < DC) atomicAdd(&s_cost[t0 * NPX + opx], a0);
      if (t1 >= 0 && t1 < DC) atomicAdd(&s_cost[t1 * NPX + opx], a1);
      if (t2 >= 0 && t2 < DC) atomicAdd(&s_cost[t2 * NPX + opx], a2);
    }
  };

  {
    int ds0 = d0 - 1;
    if (ds0 >= 0 && ds0 < DTOT)
      for (int i = tid; i < 2 * HALO; i += 256) do_coords(ds0, 0, i);
  }
  __syncthreads();

  for (int s = 0; s <= NS; ++s) {
    const int ds = d0 - 1 + s;
    const bool val_cur = (s < NS) && (ds >= 0) && (ds < DTOT);
    const bool val_next = (s + 1 < NS) && (ds + 1 >= 0) && (ds + 1 < DTOT);
    const bool val_prev = (s >= 1) && (ds - 1 >= 0) && (ds - 1 < DTOT);
    if (val_cur)
      for (int i = tid; i < VITEMS; i += 256) do_variance(s & 1, s & 1, i);
    if (val_next)
      for (int i = tid; i < 2 * HALO; i += 256) do_coords(ds + 1, (s + 1) & 1, i);
    if (val_prev) conv_accum(ds - 1, (s - 1) & 1);
    __syncthreads();
  }

  if constexpr (!EPI) {
    for (int i = tid; i < DC * NPX; i += 256) {
      int dd = i / NPX, opx = i - dd * NPX;
      int py = opx / TW, pxx = opx - py * TW;
      g_cost[(size_t)(d0 + dd) * (H * W) + (h0 + py) * W + (w0 + pxx)] = s_cost[i];
    }
  } else if (tid < NPX) {
    const int opx = tid;
    const int py = opx / TW, pxx = opx - py * TW;
    const int hp = (py + 1) * WB + (pxx + 1);
    const float base = s_dbase[hp], st = s_dstep[hp];
    float mx = -3.0e38f;
    for (int dd = 0; dd < DTOT; ++dd) mx = fmaxf(mx, s_cost[dd * NPX + opx]);
    float se = 0.f;
    for (int dd = 0; dd < DTOT; ++dd) {
      float e = expf(s_cost[dd * NPX + opx] - mx);
      s_cost[dd * NPX + opx] = e;
      se += e;
    }
    float depth = 0.f, dif = 0.f;
    for (int dd = 0; dd < DTOT; ++dd) {
      float p = s_cost[dd * NPX + opx] / se;
      s_cost[dd * NPX + opx] = p;
      depth += p * (base + (float)dd * st);
      dif += p * (float)dd;
    }
    int di = (int)dif;
    di = min(max(di, 0), DTOT - 1);
    float conf = 0.f;
    for (int k = di - 1; k <= di + 2; ++k)
      if (k >= 0 && k < DTOT) conf += s_cost[k * NPX + opx];
    float ev = 0.f;
    for (int dd = 0; dd < DTOT; ++dd) {
      float sv = base + (float)dd * st - depth;
      ev += sv * sv * s_cost[dd * NPX + opx];
    }
    ev = 1.5f * sqrtf(ev);
    int gy = h0 + py, gx = w0 + pxx;
    out_d[gy * W + gx] = depth;
    out_c[gy * W + gx] = conf;
    out_v[gy * W + gx] = ev;
  }
}

extern "C" void kernel_launch(void* const* d_in, const int* in_sizes, int n_in,
                              void* d_out, int out_size, void* d_ws, size_t ws_size,
                              hipStream_t stream) {
  const float* feats1 = (const float*)d_in[0];
  const float* feats2 = (const float*)d_in[1];
  const float* proj1 = (const float*)d_in[2];
  const float* proj2 = (const float*)d_in[3];
  const float* depthv = (const float*)d_in[4];
  const float* w1 = (const float*)d_in[6];
  const float* b1 = (const float*)d_in[7];
  const float* w2 = (const float*)d_in[8];
  const float* b2 = (const float*)d_in[9];
  float* out = (float*)d_out;
  float* ws = (float*)d_ws;

  const int nd = in_sizes[4];
  const size_t F1 = (size_t)3 * 32 * 128 * 160;     // elements
  const size_t F2 = (size_t)3 * 16 * 256 * 320;
  const size_t COST1 = (size_t)48 * 128 * 160;
  const size_t COST2 = (size_t)8 * 256 * 320;
  const size_t VAR1 = (size_t)48 * 128 * 160 * 32;  // fp16 elements
  const size_t VAR2 = (size_t)8 * 256 * 320 * 16;
  const size_t RNG2 = (size_t)2 * 256 * 320;
  const size_t HDR = 1408;
  const size_t HUGE_FLOATS =
      HDR + COST1 + COST2 + F1 / 2 + F2 / 2 + VAR1 / 2 + VAR2 / 2 + RNG2;
  const bool huge = ws_size >= HUGE_FLOATS * sizeof(float);
  const bool mid = ws_size >= (64 + COST1) * sizeof(float);

  float* d1 = out;
  float* c1 = out + 20480;
  float* v1 = out + 40960;
  float* d2 = out + 61440;
  float* c2 = out + 143360;
  float* v2 = out + 225280;

  dim3 g1c(160 / 8, 128 / 8, 8), g1f(160 / 8, 128 / 8, 1), g2(320 / 8, 256 / 8, 1);

  if (huge) {
    _Float16* w2a = (_Float16*)(ws + 64);   // 864 fp16
    _Float16* w2b = (_Float16*)(ws + 512);  // 432 fp16
    float* cost1 = ws + HDR;
    float* cost2 = cost1 + COST1;
    _Float16* f1t = (_Float16*)(cost2 + COST2);
    _Float16* f2t = (_Float16*)(cost2 + COST2 + F1 / 2);
    _Float16* var1 = (_Float16*)(cost2 + COST2 + F1 / 2 + F2 / 2);
    _Float16* var2 = (_Float16*)(cost2 + COST2 + F1 / 2 + F2 / 2 + VAR1 / 2);
    float2* rng2 = (float2*)(cost2 + COST2 + F1 / 2 + F2 / 2 + VAR1 / 2 + VAR2 / 2);
    setup_mats_kernel<<<1, 256, 0, stream>>>(proj1, proj2, depthv, nd, ws, w1, w2, w2a, w2b);
    transpose_f16_kernel<32, 128, 160><<<dim3(5, 128, 3), 256, 0, stream>>>(feats1, f1t);
    transpose_f16_kernel<16, 256, 320><<<dim3(10, 256, 3), 256, 0, stream>>>(feats2, f2t);
    // stage 1 (conv DC=6 -> grid z=8; LDS 59 KB fits 64 KB block limit)
    gather_var_kernel<32, 48, 128, 160, false>
        <<<(int)((VAR1 / 8 + 255) / 256), 256, 0, stream>>>(f1t, ws, ws + 48, nullptr, var1);
    conv_cost_kernel<32, 48, 6, 128, 160><<<g1c, 256, 0, stream>>>(
        (const uint4*)var1, w2a, b1, cost1);
    epilogue_kernel<48, 128, 160, false><<<80, 256, 0, stream>>>(
        cost1, ws + 48, nullptr, d1, c1, v1);
    // stage 2 (conv DC=8 -> grid z=1; LDS 41 KB)
    range_kernel<8, 256, 320><<<320, 256, 0, stream>>>(d1, v1, rng2);
    gather_var_kernel<16, 8, 256, 320, true>
        <<<(int)((VAR2 / 8 + 255) / 256), 256, 0, stream>>>(f2t, ws + 24, ws + 48, rng2, var2);
    conv_cost_kernel<16, 8, 8, 256, 320><<<dim3(40, 32, 1), 256, 0, stream>>>(
        (const uint4*)var2, w2b, b2, cost2);
    epilogue_kernel<8, 256, 320, true><<<320, 256, 0, stream>>>(
        cost2, ws + 48, rng2, d2, c2, v2);
  } else if (mid) {
    float* cost1 = ws + 64;
    setup_mats_kernel<<<1, 256, 0, stream>>>(proj1, proj2, depthv, nd, ws, w1, w2,
                                             nullptr, nullptr);
    cost_kernel<32, 48, 8, 8, 8, 128, 160, false, false><<<dim3(20, 16, 6), 256, 0, stream>>>(
        feats1, w1, b1, ws, ws + 48, nullptr, nullptr, cost1, nullptr, nullptr, nullptr);
    epilogue_kernel<48, 128, 160, false><<<80, 256, 0, stream>>>(
        cost1, ws + 48, nullptr, d1, c1, v1);
    cost_kernel<16, 8, 8, 8, 8, 256, 320, true, true><<<g2, 256, 0, stream>>>(
        feats2, w2, b2, ws + 24, ws + 48, d1, v1, nullptr, d2, c2, v2);
  } else {
    setup_mats_kernel<<<1, 256, 0, stream>>>(proj1, proj2, depthv, nd, ws, w1, w2,
                                             nullptr, nullptr);
    cost_kernel<32, 48, 48, 8, 8, 128, 160, false, true><<<g1f, 256, 0, stream>>>(
        feats1, w1, b1, ws, ws + 48, nullptr, nullptr, nullptr, d1, c1, v1);
    cost_kernel<16, 8, 8, 8, 8, 256, 320, true, true><<<g2, 256, 0, stream>>>(
        feats2, w2, b2, ws + 24, ws + 48, d1, v1, nullptr, d2, c2, v2);
  }
}